// Round 4
// baseline (57.275 us; speedup 1.0000x reference)
//
#include <hip/hip_runtime.h>
#include <hip/hip_bf16.h>

typedef unsigned short u16;
typedef unsigned int u32;
typedef __attribute__((ext_vector_type(8))) short bf16x8;
typedef __attribute__((ext_vector_type(4))) float f32x4;

__device__ __forceinline__ u16 f2bf(float f) {
  return __builtin_bit_cast(u16, __float2bfloat16(f));
}

__device__ __forceinline__ bf16x8 ld_frag16(const u16* p) {
  return __builtin_bit_cast(bf16x8, *reinterpret_cast<const uint4*>(p));
}

__device__ __forceinline__ void gload_lds16(const void* g, void* l) {
  __builtin_amdgcn_global_load_lds((const __attribute__((address_space(1))) void*)g,
                                   (__attribute__((address_space(3))) void*)l, 16, 0, 0);
}

// ---------------------------------------------------------------------------
// Kernel 1: Y[b] = bf16( W @ X[b] )   W:[256][256] f32, X:[256][1024] f32
// Y stored bf16 row-major [b][256][1024] in d_ws.
// BM=128, BN=64, BK=32, 4 waves (2x2), frags 4x2 of 16x16x32. (unchanged)
// ---------------------------------------------------------------------------
__global__ __launch_bounds__(256, 3) void gemm1(
    const float* __restrict__ x, const float* __restrict__ weight,
    u16* __restrict__ Y)
{
  constexpr int Nn = 1024, K = 256, BK = 32, SB = 40;
  __shared__ __align__(16) u16 As[128 * 32];   // [r][k], 16B chunks XOR-swizzled
  __shared__ __align__(16) u16 Bs[64 * SB];    // [n][k], row stride 40

  const int t = threadIdx.x;
  const int b = blockIdx.z, mt = blockIdx.y, n0 = blockIdx.x * 64;

  const float* Wp = weight + (size_t)mt * 128 * K;
  const float* Xb = x + (size_t)b * K * Nn;

  const int w = t >> 6, l = t & 63;
  const int wm = w >> 1, wn = w & 1;
  const int lr = l & 15, lg = l >> 4;

  const int ar = t >> 1, akc = (t & 1) * 16;
  const int bm = t & 63, bkq = t >> 6;
  const float* Xcol = Xb + n0 + bm;

  f32x4 acc[4][2] = {};

  for (int kt = 0; kt < K / BK; ++kt) {
    const int k0 = kt * BK;

    float4 a4[4];
#pragma unroll
    for (int uu = 0; uu < 4; ++uu)
      a4[uu] = reinterpret_cast<const float4*>(Wp + (size_t)ar * K + k0 + akc)[uu];
    union { uint4 q[2]; u16 s[16]; } ua;
#pragma unroll
    for (int uu = 0; uu < 4; ++uu) {
      ua.s[uu * 4 + 0] = f2bf(a4[uu].x); ua.s[uu * 4 + 1] = f2bf(a4[uu].y);
      ua.s[uu * 4 + 2] = f2bf(a4[uu].z); ua.s[uu * 4 + 3] = f2bf(a4[uu].w);
    }
    {
      const int c0 = akc >> 3;
      const int sw = (ar >> 1) & 3;
      uint4* Aq = reinterpret_cast<uint4*>(As);
      Aq[ar * 4 + ((c0 + 0) ^ sw)] = ua.q[0];
      Aq[ar * 4 + ((c0 + 1) ^ sw)] = ua.q[1];
    }

    float v[8];
#pragma unroll
    for (int j = 0; j < 8; ++j)
      v[j] = Xcol[(size_t)(k0 + bkq * 8 + j) * Nn];
    union { uint4 q; u16 s[8]; } ub;
#pragma unroll
    for (int j = 0; j < 8; ++j) ub.s[j] = f2bf(v[j]);
    reinterpret_cast<uint4*>(Bs)[bm * 5 + bkq] = ub.q;

    __syncthreads();

    bf16x8 af[4], bfr[2];
#pragma unroll
    for (int mi = 0; mi < 4; ++mi) {
      const int rr = wm * 64 + mi * 16 + lr;
      const int cw = lg ^ ((rr >> 1) & 3);
      af[mi] = ld_frag16(As + rr * BK + cw * 8);
    }
#pragma unroll
    for (int ni = 0; ni < 2; ++ni) {
      const int cc = wn * 32 + ni * 16 + lr;
      bfr[ni] = ld_frag16(Bs + cc * SB + lg * 8);
    }
#pragma unroll
    for (int mi = 0; mi < 4; ++mi)
#pragma unroll
      for (int ni = 0; ni < 2; ++ni)
        acc[mi][ni] = __builtin_amdgcn_mfma_f32_16x16x32_bf16(
            af[mi], bfr[ni], acc[mi][ni], 0, 0, 0);

    __syncthreads();
  }

#pragma unroll
  for (int mi = 0; mi < 4; ++mi) {
#pragma unroll
    for (int rr = 0; rr < 4; ++rr) {
      const int row = mt * 128 + wm * 64 + mi * 16 + lg * 4 + rr;
      u16* Yrow = Y + ((size_t)(b * 256 + row)) * Nn + n0;
#pragma unroll
      for (int ni = 0; ni < 2; ++ni) {
        const int col = wn * 32 + ni * 16 + lr;
        Yrow[col] = f2bf(acc[mi][ni][rr]);
      }
    }
  }
}

// ---------------------------------------------------------------------------
// Kernel 2 (v2): out = relu(Y_half @ adj_h + bias)
// BM=128, BN=64, BK=32. 512 threads (8 waves, 4m x 2n, 32x32 per wave).
// Double-buffered LDS, 2-phase pipeline: prefetch tile kt+1 (A via
// global_load_lds, B via reg-staged fp32->bf16) while computing tile kt.
// ---------------------------------------------------------------------------
__global__ __launch_bounds__(512, 4) void gemm2(
    const float* __restrict__ adj1, const float* __restrict__ adj2,
    const u16* __restrict__ Y, const float* __restrict__ bias,
    float* __restrict__ out)
{
  constexpr int Nn = 1024, BK = 32, SB = 40, NT = Nn / BK;
  __shared__ __align__(16) u16 As[2][128 * 32];   // swizzled 16B chunks
  __shared__ __align__(16) u16 Bs[2][64 * SB];    // [n][k] row stride 40

  const int t = threadIdx.x;
  const int b = blockIdx.z, h = blockIdx.y, n0 = blockIdx.x * 64;

  const float* adj = (h == 0 ? adj1 : adj2) + (size_t)b * Nn * Nn;
  const u16* Yb = Y + ((size_t)(b * 256 + h * 128)) * Nn;  // [128][1024] bf16

  const int w = t >> 6, l = t & 63;
  const int wm = w >> 1, wn = w & 1;          // 4 x 2 waves
  const int lr = l & 15, lg = l >> 4;

  // A-staging: thread t handles chunk t (of 512 16B chunks); dest is
  // wave-uniform base + lane*16 (gload_lds semantics).
  const int a_r = t >> 2, a_c = t & 3;
  const int a_cg = a_c ^ ((a_r >> 1) & 3);
  const u16* a_src = Yb + (size_t)a_r * Nn + a_cg * 8;   // + k0 at use
  const int a_dstoff = (w * 64) * 8;                      // u16 elements

  // B-staging: col bm = l, k-quad w (4 k's each)
  const int bm = l, bkq = w;
  const float* adjcol = adj + n0 + bm;
  const int b_dstoff = bm * SB + bkq * 4;                 // u16 elements

  f32x4 acc[2][2] = {};

  // ---- prologue: stage tile 0 into buf 0 ----
  gload_lds16(a_src, (void*)(&As[0][0] + a_dstoff));
  {
    float v[4];
#pragma unroll
    for (int j = 0; j < 4; ++j) v[j] = adjcol[(size_t)(bkq * 4 + j) * Nn];
    union { uint2 q; u16 s[4]; } ub;
#pragma unroll
    for (int j = 0; j < 4; ++j) ub.s[j] = f2bf(v[j]);
    *reinterpret_cast<uint2*>(&Bs[0][0] + b_dstoff) = ub.q;
  }
  __syncthreads();

  int cur = 0;
  for (int kt = 0; kt < NT - 1; ++kt) {
    const int k1 = (kt + 1) * BK;
    const int nxt = cur ^ 1;

    // ---- issue prefetch of tile kt+1 ----
    gload_lds16(a_src + k1, (void*)(&As[nxt][0] + a_dstoff));
    float v[4];
#pragma unroll
    for (int j = 0; j < 4; ++j) v[j] = adjcol[(size_t)(k1 + bkq * 4 + j) * Nn];

    // ---- compute tile kt from buf cur ----
    bf16x8 af[2], bfr[2];
#pragma unroll
    for (int mi = 0; mi < 2; ++mi) {
      const int rr = wm * 32 + mi * 16 + lr;
      const int cw = lg ^ ((rr >> 1) & 3);
      af[mi] = ld_frag16(&As[cur][0] + rr * BK + cw * 8);
    }
#pragma unroll
    for (int ni = 0; ni < 2; ++ni) {
      const int cc = wn * 32 + ni * 16 + lr;
      bfr[ni] = ld_frag16(&Bs[cur][0] + cc * SB + lg * 8);
    }
#pragma unroll
    for (int mi = 0; mi < 2; ++mi)
#pragma unroll
      for (int ni = 0; ni < 2; ++ni)
        acc[mi][ni] = __builtin_amdgcn_mfma_f32_16x16x32_bf16(
            af[mi], bfr[ni], acc[mi][ni], 0, 0, 0);

    // ---- finish B prefetch: convert + LDS write into buf nxt ----
    union { uint2 q; u16 s[4]; } ub;
#pragma unroll
    for (int j = 0; j < 4; ++j) ub.s[j] = f2bf(v[j]);
    *reinterpret_cast<uint2*>(&Bs[nxt][0] + b_dstoff) = ub.q;

    __syncthreads();   // drains vmcnt (A prefetch) + lgkm, publishes B writes
    cur = nxt;
  }

  // ---- last tile ----
  {
    bf16x8 af[2], bfr[2];
#pragma unroll
    for (int mi = 0; mi < 2; ++mi) {
      const int rr = wm * 32 + mi * 16 + lr;
      const int cw = lg ^ ((rr >> 1) & 3);
      af[mi] = ld_frag16(&As[cur][0] + rr * BK + cw * 8);
    }
#pragma unroll
    for (int ni = 0; ni < 2; ++ni) {
      const int cc = wn * 32 + ni * 16 + lr;
      bfr[ni] = ld_frag16(&Bs[cur][0] + cc * SB + lg * 8);
    }
#pragma unroll
    for (int mi = 0; mi < 2; ++mi)
#pragma unroll
      for (int ni = 0; ni < 2; ++ni)
        acc[mi][ni] = __builtin_amdgcn_mfma_f32_16x16x32_bf16(
            af[mi], bfr[ni], acc[mi][ni], 0, 0, 0);
  }

  // ---- epilogue: bias + relu, fp32 store ----
#pragma unroll
  for (int mi = 0; mi < 2; ++mi) {
#pragma unroll
    for (int rr = 0; rr < 4; ++rr) {
      const int go = h * 128 + wm * 32 + mi * 16 + lg * 4 + rr;
      const float bi = bias[go];
      float* orow = out + ((size_t)(b * 256 + go)) * Nn + n0;
#pragma unroll
      for (int ni = 0; ni < 2; ++ni) {
        const int col = wn * 32 + ni * 16 + lr;
        orow[col] = fmaxf(acc[mi][ni][rr] + bi, 0.f);
      }
    }
  }
}

extern "C" void kernel_launch(void* const* d_in, const int* in_sizes, int n_in,
                              void* d_out, int out_size, void* d_ws, size_t ws_size,
                              hipStream_t stream) {
  const float* x    = (const float*)d_in[0];
  const float* adj1 = (const float*)d_in[1];
  const float* adj2 = (const float*)d_in[2];
  const float* wgt  = (const float*)d_in[3];
  const float* bias = (const float*)d_in[4];
  float* out = (float*)d_out;
  u16* Y = (u16*)d_ws;   // 16*256*1024 bf16 = 8.4 MB

  dim3 g1(16, 2, 16);
  gemm1<<<g1, dim3(256), 0, stream>>>(x, wgt, Y);
  dim3 g2(16, 2, 16);
  gemm2<<<g2, dim3(512), 0, stream>>>(adj1, adj2, Y, bias, out);
}

// Round 5
// 52.238 us; speedup vs baseline: 1.0964x; 1.0964x over previous
//
#include <hip/hip_runtime.h>
#include <hip/hip_bf16.h>

typedef unsigned short u16;
typedef unsigned int u32;
typedef __attribute__((ext_vector_type(8))) short bf16x8;
typedef __attribute__((ext_vector_type(4))) float f32x4;

__device__ __forceinline__ u16 f2bf(float f) {
  return __builtin_bit_cast(u16, __float2bfloat16(f));
}

__device__ __forceinline__ bf16x8 ld_frag16(const u16* p) {
  return __builtin_bit_cast(bf16x8, *reinterpret_cast<const uint4*>(p));
}

__device__ __forceinline__ void gload_lds16(const void* g, void* l) {
  __builtin_amdgcn_global_load_lds((const __attribute__((address_space(1))) void*)g,
                                   (__attribute__((address_space(3))) void*)l, 16, 0, 0);
}

// Barrier that does NOT drain vmcnt: explicit lgkm drain (publish ds_writes),
// sched fence (stop LDS ops sinking past), raw s_barrier.
__device__ __forceinline__ void bar_lds() {
  asm volatile("s_waitcnt lgkmcnt(0)" ::: "memory");
  __builtin_amdgcn_sched_barrier(0);
  __builtin_amdgcn_s_barrier();
}

// ---------------------------------------------------------------------------
// Kernel 1: Y[b] = bf16( W @ X[b] )   W:[256][256] f32, X:[256][1024] f32
// Y stored bf16 row-major [b][256][1024] in d_ws. (unchanged)
// ---------------------------------------------------------------------------
__global__ __launch_bounds__(256, 3) void gemm1(
    const float* __restrict__ x, const float* __restrict__ weight,
    u16* __restrict__ Y)
{
  constexpr int Nn = 1024, K = 256, BK = 32, SB = 40;
  __shared__ __align__(16) u16 As[128 * 32];
  __shared__ __align__(16) u16 Bs[64 * SB];

  const int t = threadIdx.x;
  const int b = blockIdx.z, mt = blockIdx.y, n0 = blockIdx.x * 64;

  const float* Wp = weight + (size_t)mt * 128 * K;
  const float* Xb = x + (size_t)b * K * Nn;

  const int w = t >> 6, l = t & 63;
  const int wm = w >> 1, wn = w & 1;
  const int lr = l & 15, lg = l >> 4;

  const int ar = t >> 1, akc = (t & 1) * 16;
  const int bm = t & 63, bkq = t >> 6;
  const float* Xcol = Xb + n0 + bm;

  f32x4 acc[4][2] = {};

  for (int kt = 0; kt < K / BK; ++kt) {
    const int k0 = kt * BK;

    float4 a4[4];
#pragma unroll
    for (int uu = 0; uu < 4; ++uu)
      a4[uu] = reinterpret_cast<const float4*>(Wp + (size_t)ar * K + k0 + akc)[uu];
    union { uint4 q[2]; u16 s[16]; } ua;
#pragma unroll
    for (int uu = 0; uu < 4; ++uu) {
      ua.s[uu * 4 + 0] = f2bf(a4[uu].x); ua.s[uu * 4 + 1] = f2bf(a4[uu].y);
      ua.s[uu * 4 + 2] = f2bf(a4[uu].z); ua.s[uu * 4 + 3] = f2bf(a4[uu].w);
    }
    {
      const int c0 = akc >> 3;
      const int sw = (ar >> 1) & 3;
      uint4* Aq = reinterpret_cast<uint4*>(As);
      Aq[ar * 4 + ((c0 + 0) ^ sw)] = ua.q[0];
      Aq[ar * 4 + ((c0 + 1) ^ sw)] = ua.q[1];
    }

    float v[8];
#pragma unroll
    for (int j = 0; j < 8; ++j)
      v[j] = Xcol[(size_t)(k0 + bkq * 8 + j) * Nn];
    union { uint4 q; u16 s[8]; } ub;
#pragma unroll
    for (int j = 0; j < 8; ++j) ub.s[j] = f2bf(v[j]);
    reinterpret_cast<uint4*>(Bs)[bm * 5 + bkq] = ub.q;

    __syncthreads();

    bf16x8 af[4], bfr[2];
#pragma unroll
    for (int mi = 0; mi < 4; ++mi) {
      const int rr = wm * 64 + mi * 16 + lr;
      const int cw = lg ^ ((rr >> 1) & 3);
      af[mi] = ld_frag16(As + rr * BK + cw * 8);
    }
#pragma unroll
    for (int ni = 0; ni < 2; ++ni) {
      const int cc = wn * 32 + ni * 16 + lr;
      bfr[ni] = ld_frag16(Bs + cc * SB + lg * 8);
    }
#pragma unroll
    for (int mi = 0; mi < 4; ++mi)
#pragma unroll
      for (int ni = 0; ni < 2; ++ni)
        acc[mi][ni] = __builtin_amdgcn_mfma_f32_16x16x32_bf16(
            af[mi], bfr[ni], acc[mi][ni], 0, 0, 0);

    __syncthreads();
  }

#pragma unroll
  for (int mi = 0; mi < 4; ++mi) {
#pragma unroll
    for (int rr = 0; rr < 4; ++rr) {
      const int row = mt * 128 + wm * 64 + mi * 16 + lg * 4 + rr;
      u16* Yrow = Y + ((size_t)(b * 256 + row)) * Nn + n0;
#pragma unroll
      for (int ni = 0; ni < 2; ++ni) {
        const int col = wn * 32 + ni * 16 + lr;
        Yrow[col] = f2bf(acc[mi][ni][rr]);
      }
    }
  }
}

// ---------------------------------------------------------------------------
// Kernel 2 (v3): out = relu(Y_half @ adj_h + bias)
// BM=128, BN=64, BK=32, 512 threads (8 waves, 4m x 2n).
// 3-deep pipeline, prefetch distance 2, 4 LDS buffers, raw s_barrier +
// compiler-counted vmcnt (never drains to 0 in steady state).
// Iter j: issue A/B(j+2); cvt+ds_write B(j+1) [vmcnt(5) -> also proves
// A(j+1) landed]; compute tile j; lgkm-drain + s_barrier.
// ---------------------------------------------------------------------------
__global__ __launch_bounds__(512, 4) void gemm2(
    const float* __restrict__ adj1, const float* __restrict__ adj2,
    const u16* __restrict__ Y, const float* __restrict__ bias,
    float* __restrict__ out)
{
  constexpr int Nn = 1024, BK = 32, SB = 40, NT = Nn / BK;
  __shared__ __align__(16) u16 As[4][128 * 32];   // 4 x 8 KB
  __shared__ __align__(16) u16 Bs[4][64 * SB];    // 4 x 5 KB

  const int t = threadIdx.x;
  const int b = blockIdx.z, h = blockIdx.y, n0 = blockIdx.x * 64;

  const float* adj = (h == 0 ? adj1 : adj2) + (size_t)b * Nn * Nn;
  const u16* Yb = Y + ((size_t)(b * 256 + h * 128)) * Nn;  // [128][1024] bf16

  const int w = t >> 6, l = t & 63;
  const int wm = w >> 1, wn = w & 1;          // 4 x 2 waves
  const int lr = l & 15, lg = l >> 4;

  // A-staging: thread t handles 16B chunk t; LDS dest wave-uniform + lane*16.
  const int a_r = t >> 2, a_c = t & 3;
  const int a_cg = a_c ^ ((a_r >> 1) & 3);
  const u16* a_src = Yb + (size_t)a_r * Nn + a_cg * 8;   // + t*BK at use
  const int a_dstoff = (w * 64) * 8;                      // u16 elements

  // B-staging: col bm = l, k-quad = wave id (8 waves x 4 k = 32 k)
  const int bm = l, bkq = w;
  const float* adjcol = adj + n0 + bm;
  const int b_dstoff = bm * SB + bkq * 4;                 // u16 elements

  f32x4 acc[2][2] = {};

  auto ISSUE_A = [&](int tt) {
    gload_lds16(a_src + tt * BK, (void*)(&As[tt & 3][0] + a_dstoff));
  };
  auto LOAD_B = [&](int tt, float* v) {
#pragma unroll
    for (int j = 0; j < 4; ++j)
      v[j] = adjcol[(size_t)(tt * BK + bkq * 4 + j) * Nn];
  };
  auto WRITE_B = [&](int tt, const float* v) {
    union { uint2 q; u16 s[4]; } ub;
#pragma unroll
    for (int j = 0; j < 4; ++j) ub.s[j] = f2bf(v[j]);
    *reinterpret_cast<uint2*>(&Bs[tt & 3][0] + b_dstoff) = ub.q;
  };
  auto COMPUTE = [&](int tt) {
    const u16* Ab = &As[tt & 3][0];
    const u16* Bb = &Bs[tt & 3][0];
    bf16x8 af[2], bfr[2];
#pragma unroll
    for (int mi = 0; mi < 2; ++mi) {
      const int rr = wm * 32 + mi * 16 + lr;
      const int cw = lg ^ ((rr >> 1) & 3);
      af[mi] = ld_frag16(Ab + rr * BK + cw * 8);
    }
#pragma unroll
    for (int ni = 0; ni < 2; ++ni) {
      const int cc = wn * 32 + ni * 16 + lr;
      bfr[ni] = ld_frag16(Bb + cc * SB + lg * 8);
    }
#pragma unroll
    for (int mi = 0; mi < 2; ++mi)
#pragma unroll
      for (int ni = 0; ni < 2; ++ni)
        acc[mi][ni] = __builtin_amdgcn_mfma_f32_16x16x32_bf16(
            af[mi], bfr[ni], acc[mi][ni], 0, 0, 0);
  };

  float vA[4], vB[4];   // even tiles -> vA, odd tiles -> vB (static sets)

  // ---- prologue: tiles 0,1 in flight; publish B(0) ----
  ISSUE_A(0); LOAD_B(0, vA);
  ISSUE_A(1); LOAD_B(1, vB);
  WRITE_B(0, vA);            // forces vmcnt(5): B(0) done => A(0) in LDS
  bar_lds();

  // ---- main loop, unrolled by 2 for static vA/vB ping-pong ----
  for (int jj = 0; jj < NT / 2; ++jj) {
    const int j0 = 2 * jj;
    // even iter j0
    if (j0 + 2 < NT) { ISSUE_A(j0 + 2); LOAD_B(j0 + 2, vA); }
    WRITE_B(j0 + 1, vB);     // vmcnt(5) steady-state
    COMPUTE(j0);
    bar_lds();
    // odd iter j1
    const int j1 = j0 + 1;
    if (j1 + 2 < NT) { ISSUE_A(j1 + 2); LOAD_B(j1 + 2, vB); }
    if (j1 + 1 < NT) WRITE_B(j1 + 1, vA);
    COMPUTE(j1);
    if (jj != NT / 2 - 1) bar_lds();
  }

  // ---- epilogue: bias + relu, fp32 store ----
#pragma unroll
  for (int mi = 0; mi < 2; ++mi) {
#pragma unroll
    for (int rr = 0; rr < 4; ++rr) {
      const int go = h * 128 + wm * 32 + mi * 16 + lg * 4 + rr;
      const float bi = bias[go];
      float* orow = out + ((size_t)(b * 256 + go)) * Nn + n0;
#pragma unroll
      for (int ni = 0; ni < 2; ++ni) {
        const int col = wn * 32 + ni * 16 + lr;
        orow[col] = fmaxf(acc[mi][ni][rr] + bi, 0.f);
      }
    }
  }
}

extern "C" void kernel_launch(void* const* d_in, const int* in_sizes, int n_in,
                              void* d_out, int out_size, void* d_ws, size_t ws_size,
                              hipStream_t stream) {
  const float* x    = (const float*)d_in[0];
  const float* adj1 = (const float*)d_in[1];
  const float* adj2 = (const float*)d_in[2];
  const float* wgt  = (const float*)d_in[3];
  const float* bias = (const float*)d_in[4];
  float* out = (float*)d_out;
  u16* Y = (u16*)d_ws;   // 16*256*1024 bf16 = 8.4 MB

  dim3 g1(16, 2, 16);
  gemm1<<<g1, dim3(256), 0, stream>>>(x, wgt, Y);
  dim3 g2(16, 2, 16);
  gemm2<<<g2, dim3(512), 0, stream>>>(adj1, adj2, Y, bias, out);
}